// Round 2
// baseline (460.389 us; speedup 1.0000x reference)
//
#include <hip/hip_runtime.h>

// KANLinear fused: LayerNorm -> {relu, cubic B-spline basis} -> single bf16 MFMA GEMM.
// N=32768 rows, F=512 features, U=512 outputs. K = F*8 = 4096 (per feature:
// [relu, b0..b5, 0pad] . [base_w_row, 6 spline_w rows, 0]).
//
// Dtype-adaptive: reference is fp32, but the harness may bf16-ize. We probe the
// `grid` input's first 32-bit word on-device: fp32 grid[0] = -3.0f = 0xC0400000
// exactly; bf16-packed it is 0xC015C040. Grid-uniform branch selects the path.

#define N_ROWS 32768
#define F_DIM  512
#define U_DIM  512
#define K_DIM  4096   // F*8

typedef short short8 __attribute__((ext_vector_type(8)));
typedef float floatx4 __attribute__((ext_vector_type(4)));

__device__ __forceinline__ float bf2f(unsigned short h) {
    return __uint_as_float(((unsigned int)h) << 16);
}
__device__ __forceinline__ unsigned short f2bf(float f) {
    unsigned int u = __float_as_uint(f);
    u += 0x7fffu + ((u >> 16) & 1u);   // RNE (no NaN inputs here)
    return (unsigned short)(u >> 16);
}

__device__ __forceinline__ bool probe_bf16(const void* grid) {
    // fp32: first word is -3.0f exactly (linspace start). bf16: 0xC015C040.
    return ((const unsigned int*)grid)[0] != 0xC0400000u;
}

template <bool B16>
__device__ __forceinline__ float ldf(const void* p, int i) {
    return B16 ? bf2f(((const unsigned short*)p)[i]) : ((const float*)p)[i];
}
template <bool B16>
__device__ __forceinline__ void ld4(const void* p, int i, float* o) {
    if (B16) {
        ushort4 v = *(const ushort4*)((const unsigned short*)p + i);
        o[0] = bf2f(v.x); o[1] = bf2f(v.y); o[2] = bf2f(v.z); o[3] = bf2f(v.w);
    } else {
        float4 v = *(const float4*)((const float*)p + i);
        o[0] = v.x; o[1] = v.y; o[2] = v.z; o[3] = v.w;
    }
}

// ---------------- kernel 1: per-row LayerNorm stats (mean, rstd) ----------------
template <bool B16>
__device__ __forceinline__ void ln_stats_body(const void* __restrict__ x,
                                              float2* __restrict__ stats) {
    int wave = threadIdx.x >> 6, lane = threadIdx.x & 63;
    int row = blockIdx.x * 4 + wave;
    float v[8];
    ld4<B16>(x, row * F_DIM + lane * 8, v);
    ld4<B16>(x, row * F_DIM + lane * 8 + 4, v + 4);
    float s = 0.f, s2 = 0.f;
#pragma unroll
    for (int k = 0; k < 8; ++k) { s += v[k]; s2 += v[k] * v[k]; }
#pragma unroll
    for (int off = 32; off > 0; off >>= 1) {
        s  += __shfl_xor(s, off);
        s2 += __shfl_xor(s2, off);
    }
    if (lane == 0) {
        float mean = s * (1.0f / F_DIM);
        float var  = s2 * (1.0f / F_DIM) - mean * mean;
        stats[row] = make_float2(mean, rsqrtf(var + 1e-3f));
    }
}
__global__ __launch_bounds__(256) void ln_stats_k(const void* __restrict__ x,
                                                  const void* __restrict__ grid,
                                                  float2* __restrict__ stats) {
    if (probe_bf16(grid)) ln_stats_body<true>(x, stats);
    else                  ln_stats_body<false>(x, stats);
}

// ---------------- kernel 2: build Wt[u][k] (bf16), k = f*8 + j ----------------
// j=0 -> base_weight[f][u]; j=1..6 -> spline_weight[f*6+j-1][u]; j=7 -> 0
template <bool B16>
__device__ __forceinline__ void build_wt_body(const void* __restrict__ bw,
                                              const void* __restrict__ sw,
                                              unsigned short* __restrict__ wt) {
    int idx = blockIdx.x * 256 + threadIdx.x;  // 0 .. 512*4096
    int u = idx >> 12, k = idx & 4095;
    int f = k >> 3, j = k & 7;
    float v = 0.f;
    if (j == 0)      v = ldf<B16>(bw, f * U_DIM + u);
    else if (j < 7)  v = ldf<B16>(sw, (f * 6 + (j - 1)) * U_DIM + u);
    wt[idx] = f2bf(v);  // coalesced writes; scattered reads absorbed by L2
}
__global__ __launch_bounds__(256) void build_wt_k(const void* __restrict__ bw,
                                                  const void* __restrict__ sw,
                                                  const void* __restrict__ grid,
                                                  unsigned short* __restrict__ wt) {
    if (probe_bf16(grid)) build_wt_body<true>(bw, sw, wt);
    else                  build_wt_body<false>(bw, sw, wt);
}

// ---------------- kernel 3: fused GEMM ----------------
// 128x128 tile, BK=32 (4 features). Waves 0-1 (threads 0..127): A-gen
// (LN + analytic cubic B-spline basis -> LDS, bf16). Waves 2-3: Wt tile via
// global_load_lds (16B). 16x16x32 bf16 MFMA, 4x4 frags/wave.
template <bool B16>
__device__ __forceinline__ void kan_gemm_body(
    const void* __restrict__ x,
    const float2* __restrict__ stats,
    const unsigned short* __restrict__ wt,
    const void* __restrict__ gam,
    const void* __restrict__ bet,
    const void* __restrict__ bias,
    void* __restrict__ out) {
    __shared__ __align__(16) unsigned short Alds[128 * 32];
    __shared__ __align__(16) unsigned short Blds[128 * 32];

    const int tid = threadIdx.x;
    const int lane = tid & 63, wv = tid >> 6;
    const int ctile = blockIdx.x;  // 0..3
    const int rtile = blockIdx.y;  // 0..255

    // A-gen setup (threads 0..127 own one row each)
    float mean = 0.f, rstd = 0.f;
    int xbase = 0;
    if (tid < 128) {
        int grow = rtile * 128 + tid;
        float2 st = stats[grow];
        mean = st.x; rstd = st.y;
        xbase = grow * F_DIM;
    }

    // MFMA frag addressing
    const int wr = wv >> 1, wc = wv & 1;
    const int lr = lane & 15, lq = lane >> 4;
    const unsigned short* Abase = &Alds[(wr * 64 + lr) * 32 + lq * 8];
    const unsigned short* Bbase = &Blds[(wc * 64 + lr) * 32 + lq * 8];

    floatx4 acc[4][4];
#pragma unroll
    for (int mi = 0; mi < 4; ++mi)
#pragma unroll
        for (int ni = 0; ni < 4; ++ni) acc[mi][ni] = (floatx4){0.f, 0.f, 0.f, 0.f};

    for (int ks = 0; ks < K_DIM / 32; ++ks) {
        if (tid < 128) {
            // ---- A generation: 4 features -> 32 bf16 (4x 16B LDS writes) ----
            float xs[4], gs[4], bs[4];
            ld4<B16>(x, xbase + ks * 4, xs);
            ld4<B16>(gam, ks * 4, gs);
            ld4<B16>(bet, ks * 4, bs);
            unsigned short* ap = &Alds[tid * 32];
#pragma unroll
            for (int i = 0; i < 4; ++i) {
                float xn = (xs[i] - mean) * rstd * gs[i] + bs[i];
                float t = (xn + 3.0f) * 1.5f;  // (xn - t0)/h, h=2/3
                short8 pk;
                pk[0] = (short)f2bf(fmaxf(xn, 0.f));
#pragma unroll
                for (int j = 0; j < 6; ++j) {
                    // cardinal cubic B-spline centered at knot j+2 (t-units)
                    float a = fabsf(t - (float)(j + 2));
                    float a2 = a * a;
                    float v1 = (3.f * a * a2 - 6.f * a2 + 4.f) * (1.f / 6.f);
                    float c = 2.f - a;
                    float v2 = c * c * c * (1.f / 6.f);
                    float bb = (a < 1.f) ? v1 : v2;
                    bb = (a < 2.f) ? bb : 0.f;
                    pk[j + 1] = (short)f2bf(bb);
                }
                pk[7] = 0;
                *reinterpret_cast<short8*>(ap + i * 8) = pk;
            }
        } else {
            // ---- B staging: Wt[ctile*128 .. +128][ks*32 .. +32] -> Blds[n][k] ----
            int w2 = wv - 2;  // 0 or 1
#pragma unroll
            for (int i = 0; i < 4; ++i) {
                int c = w2 * 256 + i * 64 + lane;  // 16B chunk id, 512 total
                int n = c >> 2, q = c & 3;
                const unsigned short* gp =
                    wt + (size_t)(ctile * 128 + n) * K_DIM + ks * 32 + q * 8;
                unsigned short* lp = &Blds[(w2 * 256 + i * 64) * 8];  // wave-uniform base
                __builtin_amdgcn_global_load_lds(
                    (const __attribute__((address_space(1))) void*)gp,
                    (__attribute__((address_space(3))) void*)lp, 16, 0, 0);
            }
        }
        __syncthreads();

        short8 afr[4], bfr[4];
#pragma unroll
        for (int mi = 0; mi < 4; ++mi)
            afr[mi] = *(const short8*)(Abase + mi * 16 * 32);
#pragma unroll
        for (int ni = 0; ni < 4; ++ni)
            bfr[ni] = *(const short8*)(Bbase + ni * 16 * 32);
#pragma unroll
        for (int mi = 0; mi < 4; ++mi)
#pragma unroll
            for (int ni = 0; ni < 4; ++ni)
                acc[mi][ni] = __builtin_amdgcn_mfma_f32_16x16x32_bf16(
                    afr[mi], bfr[ni], acc[mi][ni], 0, 0, 0);
        __syncthreads();
    }

    // ---- epilogue: + bias, store ----
    float biasv[4];
#pragma unroll
    for (int ni = 0; ni < 4; ++ni)
        biasv[ni] = ldf<B16>(bias, ctile * 128 + wc * 64 + ni * 16 + lr);
#pragma unroll
    for (int mi = 0; mi < 4; ++mi)
#pragma unroll
        for (int ni = 0; ni < 4; ++ni)
#pragma unroll
            for (int r = 0; r < 4; ++r) {
                int row = rtile * 128 + wr * 64 + mi * 16 + lq * 4 + r;
                int col = ctile * 128 + wc * 64 + ni * 16 + lr;
                float val = acc[mi][ni][r] + biasv[ni];
                if (B16) ((unsigned short*)out)[(size_t)row * U_DIM + col] = f2bf(val);
                else     ((float*)out)[(size_t)row * U_DIM + col] = val;
            }
}
__global__ __launch_bounds__(256, 2) void kan_gemm(
    const void* __restrict__ x, const float2* __restrict__ stats,
    const unsigned short* __restrict__ wt, const void* __restrict__ gam,
    const void* __restrict__ bet, const void* __restrict__ bias,
    const void* __restrict__ grid, void* __restrict__ out) {
    if (probe_bf16(grid)) kan_gemm_body<true>(x, stats, wt, gam, bet, bias, out);
    else                  kan_gemm_body<false>(x, stats, wt, gam, bet, bias, out);
}

extern "C" void kernel_launch(void* const* d_in, const int* in_sizes, int n_in,
                              void* d_out, int out_size, void* d_ws, size_t ws_size,
                              hipStream_t stream) {
    const void* x    = d_in[0];
    const void* gam  = d_in[1];
    const void* bet  = d_in[2];
    const void* bw   = d_in[3];
    const void* bb   = d_in[4];
    const void* sw   = d_in[5];
    const void* grid = d_in[6];  // uniform knots; also used as the dtype probe

    float2* stats = (float2*)d_ws;                                               // 256 KB
    unsigned short* wt = (unsigned short*)((char*)d_ws + N_ROWS * sizeof(float2));  // 4 MB bf16

    hipLaunchKernelGGL(ln_stats_k, dim3(N_ROWS / 4), dim3(256), 0, stream, x, grid, stats);
    hipLaunchKernelGGL(build_wt_k, dim3(U_DIM * K_DIM / 256), dim3(256), 0, stream,
                       bw, sw, grid, wt);
    hipLaunchKernelGGL(kan_gemm, dim3(4, N_ROWS / 128), dim3(256), 0, stream,
                       x, stats, wt, gam, bet, bb, grid, d_out);
}

// Round 3
// 312.427 us; speedup vs baseline: 1.4736x; 1.4736x over previous
//
#include <hip/hip_runtime.h>
#include <hip/hip_bf16.h>

// KANLinear fused: LayerNorm -> {relu, cubic B-spline basis} -> single bf16 MFMA GEMM.
// N=32768 rows, F=512, U=512. K = F*8 = 4096 ([relu, b0..b5, 0] per feature).
// R2 restructure: 128x256 tiles, all-thread A-gen, fragment-sequential LDS layout
// (conflict-free ds_read_b128), B staged via source-permuted global_load_lds.

#define N_ROWS 32768
#define F_DIM  512
#define U_DIM  512
#define K_DIM  4096

typedef short short8 __attribute__((ext_vector_type(8)));
typedef float floatx4 __attribute__((ext_vector_type(4)));

__device__ __forceinline__ float bf2f(unsigned short h) {
    return __uint_as_float(((unsigned int)h) << 16);
}
__device__ __forceinline__ bool probe_bf16(const void* grid) {
    // fp32: grid[0] == -3.0f exactly (0xC0400000). bf16-packed: 0xC015C040.
    return ((const unsigned int*)grid)[0] != 0xC0400000u;
}
template <bool B16>
__device__ __forceinline__ float ldf(const void* p, int i) {
    return B16 ? bf2f(((const unsigned short*)p)[i]) : ((const float*)p)[i];
}
template <bool B16>
__device__ __forceinline__ void ld2(const void* p, int i, float* o) {
    if (B16) {
        ushort2 v = *(const ushort2*)((const unsigned short*)p + i);
        o[0] = bf2f(v.x); o[1] = bf2f(v.y);
    } else {
        float2 v = *(const float2*)((const float*)p + i);
        o[0] = v.x; o[1] = v.y;
    }
}
template <bool B16>
__device__ __forceinline__ void ld4(const void* p, int i, float* o) {
    if (B16) {
        ushort4 v = *(const ushort4*)((const unsigned short*)p + i);
        o[0] = bf2f(v.x); o[1] = bf2f(v.y); o[2] = bf2f(v.z); o[3] = bf2f(v.w);
    } else {
        float4 v = *(const float4*)((const float*)p + i);
        o[0] = v.x; o[1] = v.y; o[2] = v.z; o[3] = v.w;
    }
}
__device__ __forceinline__ unsigned int pk2(float lo, float hi) {
    __hip_bfloat162 h = __float22bfloat162_rn(make_float2(lo, hi));
    return *reinterpret_cast<unsigned int*>(&h);
}

// ---------------- kernel 1: per-row LayerNorm stats ----------------
template <bool B16>
__device__ __forceinline__ void ln_stats_body(const void* __restrict__ x,
                                              float2* __restrict__ stats) {
    int wave = threadIdx.x >> 6, lane = threadIdx.x & 63;
    int row = blockIdx.x * 4 + wave;
    float v[8];
    ld4<B16>(x, row * F_DIM + lane * 8, v);
    ld4<B16>(x, row * F_DIM + lane * 8 + 4, v + 4);
    float s = 0.f, s2 = 0.f;
#pragma unroll
    for (int k = 0; k < 8; ++k) { s += v[k]; s2 += v[k] * v[k]; }
#pragma unroll
    for (int off = 32; off > 0; off >>= 1) {
        s  += __shfl_xor(s, off);
        s2 += __shfl_xor(s2, off);
    }
    if (lane == 0) {
        float mean = s * (1.0f / F_DIM);
        float var  = s2 * (1.0f / F_DIM) - mean * mean;
        stats[row] = make_float2(mean, rsqrtf(var + 1e-3f));
    }
}
__global__ __launch_bounds__(256) void ln_stats_k(const void* __restrict__ x,
                                                  const void* __restrict__ grid,
                                                  float2* __restrict__ stats) {
    if (probe_bf16(grid)) ln_stats_body<true>(x, stats);
    else                  ln_stats_body<false>(x, stats);
}

// ---------------- kernel 2: build Wt[u][k] (bf16), k = f*8 + j ----------------
// Coalesced reads (lanes = consecutive u); each thread writes one 64B run of wt.
template <bool B16>
__device__ __forceinline__ void build_wt_body(const void* __restrict__ bw,
                                              const void* __restrict__ sw,
                                              unsigned short* __restrict__ wt) {
    int idx = blockIdx.x * 256 + threadIdx.x;  // 0 .. 512*128
    int u = idx & 511;
    int fq = idx >> 9;  // 0..127 -> features fq*4 .. fq*4+3
#pragma unroll
    for (int i = 0; i < 4; ++i) {
        int f = fq * 4 + i;
        uint4 w;
        w.x = pk2(ldf<B16>(bw, f * U_DIM + u),            ldf<B16>(sw, (f * 6 + 0) * U_DIM + u));
        w.y = pk2(ldf<B16>(sw, (f * 6 + 1) * U_DIM + u),  ldf<B16>(sw, (f * 6 + 2) * U_DIM + u));
        w.z = pk2(ldf<B16>(sw, (f * 6 + 3) * U_DIM + u),  ldf<B16>(sw, (f * 6 + 4) * U_DIM + u));
        w.w = pk2(ldf<B16>(sw, (f * 6 + 5) * U_DIM + u),  0.f);
        *(uint4*)(wt + (size_t)u * K_DIM + f * 8) = w;
    }
}
__global__ __launch_bounds__(256) void build_wt_k(const void* __restrict__ bw,
                                                  const void* __restrict__ sw,
                                                  const void* __restrict__ grid,
                                                  unsigned short* __restrict__ wt) {
    if (probe_bf16(grid)) build_wt_body<true>(bw, sw, wt);
    else                  build_wt_body<false>(bw, sw, wt);
}

// ---------------- kernel 3: fused GEMM ----------------
// 128 rows x 256 cols per block, BK=32. 4 waves, each 64x128 (acc 4x8 frags).
// LDS slot layout (16B slots): slot(R,q) = ((R>>4)*4+q)*16 + (R&15) -> frag reads
// are lane-sequential 1KB ds_read_b128 (conflict-free). All threads do A-gen
// (2 features each) AND issue 4 global_load_lds for B with permuted sources.
template <bool B16>
__device__ __forceinline__ void kan_gemm_body(
    const void* __restrict__ x,
    const float2* __restrict__ stats,
    const unsigned short* __restrict__ wt,
    const void* __restrict__ gam,
    const void* __restrict__ bet,
    const void* __restrict__ bias,
    void* __restrict__ out) {
    __shared__ __align__(16) unsigned short Alds[128 * 32];  // 8 KB
    __shared__ __align__(16) unsigned short Blds[256 * 32];  // 16 KB

    const int tid = threadIdx.x;
    const int lane = tid & 63, wv = tid >> 6;
    const int ctile = blockIdx.x;  // 0..1
    const int rtile = blockIdx.y;  // 0..255

    // A-gen: thread owns (row = tid&127, feature-pair fg = tid>>7)
    const int arow = tid & 127, fg = tid >> 7;
    const int grow = rtile * 128 + arow;
    float2 st = stats[grow];
    const float mean = st.x, rstd = st.y;
    const int xoff = grow * F_DIM + fg * 2;
    const int goff = fg * 2;
    const int aslot0 = ((arow >> 4) * 4 + fg * 2) * 16 + (arow & 15);
    uint4* aptr0 = (uint4*)&Alds[aslot0 * 8];
    uint4* aptr1 = (uint4*)&Alds[(aslot0 + 16) * 8];

    // B staging: slot s = wv*256 + i*64 + lane holds Wt col C, kchunk q
    const unsigned short* gsrc[4];
    unsigned short* ldst[4];
#pragma unroll
    for (int i = 0; i < 4; ++i) {
        int s = wv * 256 + i * 64 + lane;
        int C = ((s >> 6) << 4) | (s & 15);
        int q = (s >> 4) & 3;
        gsrc[i] = wt + (size_t)(ctile * 256 + C) * K_DIM + q * 8;
        ldst[i] = &Blds[(wv * 256 + i * 64) * 8];  // wave-uniform base
    }

    // MFMA coords: wave covers rows wr*64..+64, cols wc*128..+128
    const int wr = wv >> 1, wc = wv & 1;
    const int lr = lane & 15, lq = lane >> 4;

    floatx4 acc[4][8];
#pragma unroll
    for (int mi = 0; mi < 4; ++mi)
#pragma unroll
        for (int ni = 0; ni < 8; ++ni) acc[mi][ni] = (floatx4){0.f, 0.f, 0.f, 0.f};

    for (int ks = 0; ks < K_DIM / 32; ++ks) {
        // ---- B staging (4 x 16B per wave) ----
#pragma unroll
        for (int i = 0; i < 4; ++i)
            __builtin_amdgcn_global_load_lds(
                (const __attribute__((address_space(1))) void*)(gsrc[i] + ks * 32),
                (__attribute__((address_space(3))) void*)ldst[i], 16, 0, 0);

        // ---- A generation: 2 features -> 2 x 16B ----
        float xs[2], gs[2], bs[2];
        ld2<B16>(x, xoff + ks * 4, xs);
        ld2<B16>(gam, goff + ks * 4, gs);
        ld2<B16>(bet, goff + ks * 4, bs);
        uint4 pkv[2];
#pragma unroll
        for (int i = 0; i < 2; ++i) {
            float xn = fmaf(xs[i] - mean, rstd * gs[i], bs[i]);
            float tt = fmaf(xn, 1.5f, 4.5f);  // t = (xn+3)/h, h=2/3
            float bb[6];
#pragma unroll
            for (int j = 0; j < 6; ++j) {
                float d = tt - (float)(j + 2);
                float a = fabsf(d);
                float a2 = d * d;
                float v1 = fmaf(fmaf(0.5f, a, -1.0f), a2, 0.66666669f);
                float c = fmaxf(2.0f - a, 0.0f);  // clamps a>=2 to 0 via cube
                float v2 = c * c * c * (1.0f / 6.0f);
                bb[j] = (a < 1.0f) ? v1 : v2;
            }
            pkv[i].x = pk2(fmaxf(xn, 0.f), bb[0]);
            pkv[i].y = pk2(bb[1], bb[2]);
            pkv[i].z = pk2(bb[3], bb[4]);
            pkv[i].w = pk2(bb[5], 0.f);
        }
        *aptr0 = pkv[0];
        *aptr1 = pkv[1];
        __syncthreads();

        // ---- fragments (lane-sequential, conflict-free) ----
        short8 afr[4], bfr[8];
#pragma unroll
        for (int mi = 0; mi < 4; ++mi)
            afr[mi] = *(const short8*)&Alds[((wr * 4 + mi) * 64 + lane) * 8];
#pragma unroll
        for (int ni = 0; ni < 8; ++ni)
            bfr[ni] = *(const short8*)&Blds[((wc * 8 + ni) * 64 + lane) * 8];
#pragma unroll
        for (int mi = 0; mi < 4; ++mi)
#pragma unroll
            for (int ni = 0; ni < 8; ++ni)
                acc[mi][ni] = __builtin_amdgcn_mfma_f32_16x16x32_bf16(
                    afr[mi], bfr[ni], acc[mi][ni], 0, 0, 0);
        __syncthreads();
    }

    // ---- epilogue: + bias, store ----
    float biasv[8];
#pragma unroll
    for (int ni = 0; ni < 8; ++ni)
        biasv[ni] = ldf<B16>(bias, ctile * 256 + wc * 128 + ni * 16 + lr);
#pragma unroll
    for (int mi = 0; mi < 4; ++mi)
#pragma unroll
        for (int ni = 0; ni < 8; ++ni)
#pragma unroll
            for (int r = 0; r < 4; ++r) {
                int row = rtile * 128 + wr * 64 + mi * 16 + lq * 4 + r;
                int col = ctile * 256 + wc * 128 + ni * 16 + lr;
                float val = acc[mi][ni][r] + biasv[ni];
                if (B16) ((unsigned short*)out)[(size_t)row * U_DIM + col] =
                    (unsigned short)(pk2(val, 0.f) & 0xffffu);
                else ((float*)out)[(size_t)row * U_DIM + col] = val;
            }
}
__global__ __launch_bounds__(256, 2) void kan_gemm(
    const void* __restrict__ x, const float2* __restrict__ stats,
    const unsigned short* __restrict__ wt, const void* __restrict__ gam,
    const void* __restrict__ bet, const void* __restrict__ bias,
    const void* __restrict__ grid, void* __restrict__ out) {
    if (probe_bf16(grid)) kan_gemm_body<true>(x, stats, wt, gam, bet, bias, out);
    else                  kan_gemm_body<false>(x, stats, wt, gam, bet, bias, out);
}

extern "C" void kernel_launch(void* const* d_in, const int* in_sizes, int n_in,
                              void* d_out, int out_size, void* d_ws, size_t ws_size,
                              hipStream_t stream) {
    const void* x    = d_in[0];
    const void* gam  = d_in[1];
    const void* bet  = d_in[2];
    const void* bw   = d_in[3];
    const void* bb   = d_in[4];
    const void* sw   = d_in[5];
    const void* grid = d_in[6];  // uniform knots; also the dtype probe

    float2* stats = (float2*)d_ws;                                                  // 256 KB
    unsigned short* wt = (unsigned short*)((char*)d_ws + N_ROWS * sizeof(float2));  // 4 MB bf16

    hipLaunchKernelGGL(ln_stats_k, dim3(N_ROWS / 4), dim3(256), 0, stream, x, grid, stats);
    hipLaunchKernelGGL(build_wt_k, dim3(U_DIM * 128 / 256), dim3(256), 0, stream,
                       bw, sw, grid, wt);
    hipLaunchKernelGGL(kan_gemm, dim3(2, N_ROWS / 128), dim3(256), 0, stream,
                       x, stats, wt, gam, bet, bb, grid, d_out);
}